// Round 11
// baseline (686.292 us; speedup 1.0000x reference)
//
#include <hip/hip_runtime.h>
#include <hip/hip_bf16.h>

// ---------------------------------------------------------------------------
// GraphSAGE 2-layer (mean agg) + edge MLP predictor.
// Round 11: cooperative LDS-atomic aggregation (no per-lane degree loops).
//  - k_s4 emits packed eidx = src | (dst&255)<<16.
//  - k_gemm_fused: block's edge run streamed edge-uniformly; 16-lane groups
//    accumulate 64-dim halves into sAgg[128][68] via ds_add_f32 (2 passes);
//    fragments extracted from LDS; W half-staged over the same region.
//    Register arrays gone -> launch_bounds(256,3) without spills.
//  - k_agg3: same pattern, sAgg[256][9], one edge/thread.
// score[e] = ps[src] + pd[dst] + bconst
// ---------------------------------------------------------------------------

typedef __attribute__((ext_vector_type(8))) short bf16x8;
typedef __attribute__((ext_vector_type(4))) float f32x4;

static __device__ __forceinline__ float bf16lo(unsigned u) {
    return __uint_as_float(u << 16);
}
static __device__ __forceinline__ float bf16hi(unsigned u) {
    return __uint_as_float(u & 0xffff0000u);
}
static __device__ __forceinline__ unsigned short f2bf(float f) {
    unsigned u = __float_as_uint(f);
    unsigned r = 0x7fffu + ((u >> 16) & 1u);  // round to nearest even
    return (unsigned short)((u + r) >> 16);
}
static __device__ __forceinline__ unsigned pack_bf162(float a, float b) {
    return (unsigned)f2bf(a) | ((unsigned)f2bf(b) << 16);
}

#define SORT_BLOCKS 128   // S1/S3 chunk blocks

// ---------------- fused misc: cvt | S1 bucket-hist | Wt1 prep | Wc prep -----
__global__ __launch_bounds__(256) void k_misc(
    const float* __restrict__ x, unsigned short* __restrict__ xb,
    const int* __restrict__ dst, int* __restrict__ H,
    const float* __restrict__ W1s, const float* __restrict__ W1n,
    unsigned short* __restrict__ Wt1,
    const float* __restrict__ W2s, const float* __restrict__ W2n,
    const float* __restrict__ Wp, const float* __restrict__ b2,
    const float* __restrict__ bp, float* __restrict__ Wc,
    float* __restrict__ bconst, int N, int E, int CHUNK)
{
    const int nCvt = (N * 32 + 255) / 256;
    const int b = blockIdx.x;
    const int t = threadIdx.x;

    if (b < nCvt) {
        int i = b * 256 + t;
        if (i < N * 32) {
            float4 v = ((const float4*)x)[i];
            uint2 o;
            o.x = pack_bf162(v.x, v.y);
            o.y = pack_bf162(v.z, v.w);
            *(uint2*)(xb + (size_t)i * 4) = o;
        }
    } else if (b < nCvt + SORT_BLOCKS) {
        // S1: LDS histogram of dst>>8 for this block's edge chunk
        __shared__ int hist[256];
        hist[t] = 0;
        __syncthreads();
        int blk = b - nCvt;
        int start = blk * CHUNK;
        int end = min(start + CHUNK, E);
        for (int e = start + t; e < end; e += 256)
            atomicAdd(&hist[((unsigned)dst[e]) >> 8], 1);
        __syncthreads();
        H[blk * 256 + t] = hist[t];
    } else if (b < nCvt + SORT_BLOCKS + 128) {
        int id = (b - nCvt - SORT_BLOCKS) * 256 + t;  // 32768 total
        int k = id >> 7, n = id & 127;
        float v = (k < 128) ? W1s[k * 128 + n] : W1n[(k - 128) * 128 + n];
        Wt1[n * 256 + k] = f2bf(v);
    } else {
        // Wc[c][j]: j 0-2 u=W2s@Wp_top, 3-5 t=W2n@Wp_top,
        //             6-8 v=W2s@Wp_bot, 9-11 w=W2n@Wp_bot; bconst
        for (int id = t; id < 1539; id += 256) {
            if (id < 1536) {
                int c = id / 12, j = id % 12;
                int q = j / 3, jj = j % 3;
                const float* W2 = (q == 0 || q == 2) ? W2s : W2n;
                int wpoff = (q < 2) ? 0 : 128;
                float s = 0.f;
                for (int m = 0; m < 128; ++m)
                    s += W2[c * 128 + m] * Wp[(wpoff + m) * 3 + jj];
                Wc[c * 12 + j] = s;
            } else {
                int jj = id - 1536;
                float s = bp[jj];
                for (int m = 0; m < 128; ++m)
                    s += b2[m] * (Wp[m * 3 + jj] + Wp[(128 + m) * 3 + jj]);
                bconst[jj] = s;
            }
        }
    }
}

// ---------------- S3 (with fused S2): scatter edges into bucket regions -----
__global__ __launch_bounds__(256) void k_s3(const int* __restrict__ src,
                                            const int* __restrict__ dst,
                                            const int* __restrict__ H,
                                            int* __restrict__ packed,
                                            int* __restrict__ bucketBase,
                                            int E, int CHUNK) {
    __shared__ int lt[256];
    __shared__ int cur[256];
    const int t = threadIdx.x, blk = blockIdx.x;
    int tot = 0, pre = 0;
    for (int b = 0; b < SORT_BLOCKS; ++b) {
        int h = H[b * 256 + t];
        pre += (b < blk) ? h : 0;
        tot += h;
    }
    lt[t] = tot;
    __syncthreads();
    for (int off = 1; off < 256; off <<= 1) {
        int u = (t >= off) ? lt[t - off] : 0;
        __syncthreads();
        lt[t] += u;
        __syncthreads();
    }
    int excl = lt[t] - tot;
    cur[t] = excl + pre;
    if (blk == 0) {
        bucketBase[t] = excl;
        if (t == 0) bucketBase[256] = E;
    }
    __syncthreads();
    int start = blk * CHUNK, end = min(start + CHUNK, E);
    for (int e = start + t; e < end; e += 256) {
        int d = dst[e];
        int p = atomicAdd(&cur[((unsigned)d) >> 8], 1);
        packed[p] = (src[e] & 0xFFFF) | ((d & 255) << 16);  // N<=65536
    }
}

// ---------------- S4: per-bucket counting sort + CSR finalize ---------------
// eidx entries keep the packed form: src | (dst&255)<<16.
__global__ __launch_bounds__(256) void k_s4(const int* __restrict__ packed,
                                            const int* __restrict__ bucketBase,
                                            int* __restrict__ eidx,
                                            int* __restrict__ cursor,
                                            float* __restrict__ fdeg,
                                            float* __restrict__ invdeg, int N) {
    const int t = threadIdx.x, b = blockIdx.x;
    const int rb = bucketBase[b], re = bucketBase[b + 1];
    __shared__ int cnt[256];
    __shared__ int lt[256];
    __shared__ int cur[256];
    cnt[t] = 0;
    __syncthreads();
    for (int i = rb + t; i < re; i += 256)
        atomicAdd(&cnt[(packed[i] >> 16) & 255], 1);
    __syncthreads();
    int v = cnt[t];
    lt[t] = v;
    __syncthreads();
    for (int off = 1; off < 256; off <<= 1) {
        int u = (t >= off) ? lt[t - off] : 0;
        __syncthreads();
        lt[t] += u;
        __syncthreads();
    }
    int excl = lt[t] - v;
    int node = b * 256 + t;
    if (node < N) {
        cursor[node] = rb + excl + v;  // end offset
        fdeg[node] = (float)v;
        invdeg[node] = 1.0f / fmaxf((float)v, 1.0f);
    }
    cur[t] = rb + excl;
    __syncthreads();
    for (int i = rb + t; i < re; i += 256) {
        int p = packed[i];
        int pos = atomicAdd(&cur[(p >> 16) & 255], 1);
        eidx[pos] = p;   // keep src | dstLow<<16
    }
}

// ---------------- fused gather-aggregate + MFMA GEMM + projection -----------
// Gather: the block's contiguous dst-sorted edge run is streamed edge-
// uniformly; each 16-lane group handles one edge per iter (coalesced 128B
// half-row), accumulating into sAgg[128][68] fp32 via LDS atomics (2 passes
// of 64 dims). Fragments extracted from LDS. Then W half-staged over the
// same LDS region; MFMA; epilogue projects h -> P.
__global__ __launch_bounds__(256, 3) void k_gemm_fused(
    const unsigned short* __restrict__ xb,
    const int* __restrict__ eidx, const int* __restrict__ cursor,
    const float* __restrict__ fdeg, const float* __restrict__ invdeg,
    const unsigned short* __restrict__ Wt, const float* __restrict__ bias,
    const float* __restrict__ Wc, float* __restrict__ P, int N)
{
    __shared__ __align__(16) char sMem[128 * 68 * 4];  // 34816B: agg tile / W
    __shared__ float sWc[1536];
    float* sAgg = (float*)sMem;
    char* sW = sMem;

    const int t = threadIdx.x;
    const int wave = t >> 6, lane = t & 63;
    const int nodeBase = blockIdx.x * 128 + wave * 32;
    const int lrow = lane & 15, lk = lane >> 4;
    const int r0 = nodeBase + lrow, r1 = nodeBase + 16 + lrow;

    const int nb0 = blockIdx.x * 128;
    const int lastN = min(nb0 + 127, N - 1);
    const int estart = cursor[nb0] - (int)fdeg[nb0];
    const int eend = cursor[lastN];
    const int dstAdj = (blockIdx.x & 1) << 7;   // dstLoc = (dst&255) - dstAdj

    const int grp = t >> 4;   // 0..15: one edge per group per iteration
    const int gl = t & 15;    // lane within group: 4 dims each

    const float sc0 = (r0 < N) ? invdeg[r0] : 0.f;
    const float sc1 = (r1 < N) ? invdeg[r1] : 0.f;
    const int row0 = wave * 32 + lrow, row1 = wave * 32 + 16 + lrow;

    union { bf16x8 v; unsigned u[4]; } afrag0[4], afrag1[4];

    for (int half = 0; half < 2; ++half) {
        for (int i = t; i < 128 * 68; i += 256) sAgg[i] = 0.f;
        __syncthreads();
        for (int i = estart + grp; i < eend; i += 16) {
            int pk = eidx[i];
            int dl = ((pk >> 16) & 255) - dstAdj;
            uint2 v = *(const uint2*)(xb + (size_t)(pk & 0xFFFF) * 128 +
                                      half * 64 + gl * 4);
            float* dd = &sAgg[dl * 68 + gl * 4];
            atomicAdd(dd + 0, bf16lo(v.x));
            atomicAdd(dd + 1, bf16hi(v.x));
            atomicAdd(dd + 2, bf16lo(v.y));
            atomicAdd(dd + 3, bf16hi(v.y));
        }
        __syncthreads();
        // extract this half's two K-subblocks (dims ksb2*32 + lk*8 .. +7)
#pragma unroll
        for (int ksb2 = 0; ksb2 < 2; ++ksb2) {
            int ksb = half * 2 + ksb2;
            const float* p0 = &sAgg[row0 * 68 + ksb2 * 32 + lk * 8];
            const float* p1 = &sAgg[row1 * 68 + ksb2 * 32 + lk * 8];
            float4 a = *(const float4*)(p0);
            float4 b = *(const float4*)(p0 + 4);
            afrag0[ksb].u[0] = pack_bf162(a.x * sc0, a.y * sc0);
            afrag0[ksb].u[1] = pack_bf162(a.z * sc0, a.w * sc0);
            afrag0[ksb].u[2] = pack_bf162(b.x * sc0, b.y * sc0);
            afrag0[ksb].u[3] = pack_bf162(b.z * sc0, b.w * sc0);
            float4 c = *(const float4*)(p1);
            float4 d = *(const float4*)(p1 + 4);
            afrag1[ksb].u[0] = pack_bf162(c.x * sc1, c.y * sc1);
            afrag1[ksb].u[1] = pack_bf162(c.z * sc1, c.w * sc1);
            afrag1[ksb].u[2] = pack_bf162(d.x * sc1, d.y * sc1);
            afrag1[ksb].u[3] = pack_bf162(d.z * sc1, d.w * sc1);
        }
        __syncthreads();
    }

    f32x4 acc[2][8];
#pragma unroll
    for (int rs = 0; rs < 2; ++rs)
#pragma unroll
        for (int nb = 0; nb < 8; ++nb) acc[rs][nb] = (f32x4){0.f, 0.f, 0.f, 0.f};

    // ---- MFMA: two K-halves of W staged over the same LDS region ----
    for (int half = 0; half < 2; ++half) {
        __syncthreads();
#pragma unroll
        for (int i = 0; i < 8; ++i) {
            int idx = i * 256 + t;          // 2048 chunks of 16B
            int n = idx >> 4;               // row 0..127
            int c = (idx & 15) << 4;        // byte col within 256B half
            int sw = (n << 8) | (c ^ ((n & 7) << 4));
            *(uint4*)&sW[sw] =
                *(const uint4*)((const char*)Wt + n * 512 + half * 256 + c);
        }
        if (half == 0)
            for (int i = t; i < 1536; i += 256) sWc[i] = Wc[i];
        __syncthreads();

        for (int ks2 = 0; ks2 < 4; ++ks2) {
            const int ks = half * 4 + ks2;
            bf16x8 a0, a1;
            if (half == 0) {
                const int kk = ks * 32 + lk * 8;
                a0 = (bf16x8){};
                a1 = (bf16x8){};
                if (r0 < N) a0 = *(const bf16x8*)(xb + (size_t)r0 * 128 + kk);
                if (r1 < N) a1 = *(const bf16x8*)(xb + (size_t)r1 * 128 + kk);
            } else {
                a0 = afrag0[ks2].v;
                a1 = afrag1[ks2].v;
            }
            const int cbase = ks2 * 64 + lk * 16;  // byte col within 256B half
#pragma unroll
            for (int nb = 0; nb < 8; ++nb) {
                int n = nb * 16 + lrow;
                int sw = (n << 8) | (cbase ^ ((n & 7) << 4));
                bf16x8 b = *(const bf16x8*)&sW[sw];
                acc[0][nb] = __builtin_amdgcn_mfma_f32_16x16x32_bf16(a0, b, acc[0][nb], 0, 0, 0);
                acc[1][nb] = __builtin_amdgcn_mfma_f32_16x16x32_bf16(a1, b, acc[1][nb], 0, 0, 0);
            }
        }
    }

    // Epilogue: C/D layout col = lane&15, row = (lane>>4)*4 + reg [m89].
    // P row layout: self u0..2,v0 at [0..3], v1,v2 at [4..5];
    //               neigh t0..2,w0 at [8..11], w1,w2 at [12..13].
#pragma unroll
    for (int rs = 0; rs < 2; ++rs) {
        float hval[8][4];
#pragma unroll
        for (int nb = 0; nb < 8; ++nb) {
            float bv = bias[nb * 16 + lrow];
#pragma unroll
            for (int r = 0; r < 4; ++r)
                hval[nb][r] = fmaxf(acc[rs][nb][r] + bv, 0.f);
        }
#pragma unroll
        for (int r = 0; r < 4; ++r) {
            float pj[12];
#pragma unroll
            for (int j = 0; j < 12; ++j) pj[j] = 0.f;
#pragma unroll
            for (int nb = 0; nb < 8; ++nb) {
                float hv = hval[nb][r];
                const float* wrow = &sWc[(nb * 16 + lrow) * 12];
#pragma unroll
                for (int j = 0; j < 12; ++j) pj[j] += hv * wrow[j];
            }
#pragma unroll
            for (int off = 8; off; off >>= 1) {
#pragma unroll
                for (int j = 0; j < 12; ++j) pj[j] += __shfl_xor(pj[j], off, 64);
            }
            int node = nodeBase + rs * 16 + lk * 4 + r;
            if (lrow == 0 && node < N) {
                float* prow = &P[(size_t)node * 16];
                *(float4*)(prow + 0)  = make_float4(pj[0], pj[1], pj[2], pj[6]);
                *(float4*)(prow + 4)  = make_float4(pj[7], pj[8], 0.f, 0.f);
                *(float4*)(prow + 8)  = make_float4(pj[3], pj[4], pj[5], pj[9]);
                *(float4*)(prow + 12) = make_float4(pj[10], pj[11], 0.f, 0.f);
            }
        }
    }
}

// ---------------- 6-dim aggregation + finalize ps/pd -----------------------
// Block b owns bucket b (256 nodes, contiguous edge run). One edge/thread,
// LDS-atomic accumulation into sAgg[256][9]; then per-node finalize.
__global__ __launch_bounds__(256) void k_agg3(const float* __restrict__ P,
                                              const int* __restrict__ eidx,
                                              const int* __restrict__ bucketBase,
                                              const float* __restrict__ invdeg,
                                              float4* __restrict__ ps4,
                                              float4* __restrict__ pd4, int N) {
    __shared__ float sAgg[256 * 9];
    const int t = threadIdx.x, b = blockIdx.x;
    const int rb = bucketBase[b], re = bucketBase[b + 1];
    for (int i = t; i < 256 * 9; i += 256) sAgg[i] = 0.f;
    __syncthreads();
    for (int i = rb + t; i < re; i += 256) {
        int pk = eidx[i];
        int s = pk & 0xFFFF;
        int dl = (pk >> 16) & 255;
        float4 u0 = *(const float4*)&P[(size_t)s * 16 + 8];
        float2 u1 = *(const float2*)&P[(size_t)s * 16 + 12];
        float* dd = &sAgg[dl * 9];
        atomicAdd(dd + 0, u0.x);
        atomicAdd(dd + 1, u0.y);
        atomicAdd(dd + 2, u0.z);
        atomicAdd(dd + 3, u0.w);
        atomicAdd(dd + 4, u1.x);
        atomicAdd(dd + 5, u1.y);
    }
    __syncthreads();
    int g = b * 256 + t;
    if (g < N) {
        float sc = invdeg[g];
        const float* dd = &sAgg[t * 9];
        float4 s0v = *(const float4*)&P[(size_t)g * 16];      // u0,u1,u2,v0
        float2 s1v = *(const float2*)&P[(size_t)g * 16 + 4];  // v1,v2
        ps4[g] = make_float4(s0v.x + dd[0] * sc, s0v.y + dd[1] * sc,
                             s0v.z + dd[2] * sc, 0.f);
        pd4[g] = make_float4(s0v.w + dd[3] * sc, s1v.x + dd[4] * sc,
                             s1v.y + dd[5] * sc, 0.f);
    }
}

__global__ void k_edge(const float4* __restrict__ ps4, const float4* __restrict__ pd4,
                       const int* __restrict__ src, const int* __restrict__ dst,
                       const float* __restrict__ bconst, float* __restrict__ out, int E)
{
    int e = blockIdx.x * blockDim.x + threadIdx.x;
    if (e >= E) return;
    float4 a = ps4[src[e]];
    float4 b = pd4[dst[e]];
    out[(size_t)e * 3 + 0] = a.x + b.x + bconst[0];
    out[(size_t)e * 3 + 1] = a.y + b.y + bconst[1];
    out[(size_t)e * 3 + 2] = a.z + b.z + bconst[2];
}

extern "C" void kernel_launch(void* const* d_in, const int* in_sizes, int n_in,
                              void* d_out, int out_size, void* d_ws, size_t ws_size,
                              hipStream_t stream)
{
    const float* x   = (const float*)d_in[0];
    // d_in[1] = e (edge features) — unused by the reference score
    const int*   src = (const int*)d_in[2];
    const int*   dst = (const int*)d_in[3];
    const float* W1s = (const float*)d_in[4];
    const float* W1n = (const float*)d_in[5];
    const float* b1  = (const float*)d_in[6];
    const float* W2s = (const float*)d_in[7];
    const float* W2n = (const float*)d_in[8];
    const float* b2  = (const float*)d_in[9];
    const float* Wp  = (const float*)d_in[10];
    const float* bp  = (const float*)d_in[11];
    const int N = in_sizes[0] / 128;
    const int E = in_sizes[2];
    float* out = (float*)d_out;

    const int NB = (N + 255) / 256;            // dst buckets (<=256 for N<=65536)
    const int CHUNK = (E + SORT_BLOCKS - 1) / SORT_BLOCKS;

    // ---- workspace carve (256B aligned chunks) ----
    char* wsp = (char*)d_ws;
    auto alloc = [&](size_t bytes) { char* p = wsp; wsp += (bytes + 255) & ~(size_t)255; return p; };
    float* fdeg     = (float*)alloc((size_t)N * 4);
    float* invdeg   = (float*)alloc((size_t)N * 4);
    int*   cursor   = (int*)alloc((size_t)N * 4);
    int*   eidx     = (int*)alloc((size_t)E * 4);
    int*   packed   = (int*)alloc((size_t)E * 4);
    int*   H        = (int*)alloc((size_t)SORT_BLOCKS * 256 * 4);
    int*   bucketBase = (int*)alloc(260 * 4);
    unsigned short* xb  = (unsigned short*)alloc((size_t)N * 128 * 2);
    unsigned short* Wt1 = (unsigned short*)alloc(256 * 128 * 2);
    float* Wc     = (float*)alloc(1536 * 4);
    float* bconst = (float*)alloc(256);
    float* P      = (float*)alloc((size_t)N * 16 * 4);   // padded 64B rows
    float* ps4    = (float*)alloc((size_t)N * 16);
    float* pd4    = (float*)alloc((size_t)N * 16);

    // fused cvt | S1 bucket-hist | weight prep (all independent)
    const int nCvt = (N * 32 + 255) / 256;
    k_misc<<<nCvt + SORT_BLOCKS + 129, 256, 0, stream>>>(
        x, xb, dst, H, W1s, W1n, Wt1, W2s, W2n, Wp, b2, bp, Wc, bconst, N, E, CHUNK);

    // atomic-free CSR build (s2 fused into s3)
    k_s3<<<SORT_BLOCKS, 256, 0, stream>>>(src, dst, H, packed, bucketBase, E, CHUNK);
    k_s4<<<NB, 256, 0, stream>>>(packed, bucketBase, eidx, cursor, fdeg, invdeg, N);

    // layer 1 + projection, fully fused (agg via LDS atomics, h never stored)
    k_gemm_fused<<<(N + 127) / 128, 256, 0, stream>>>(xb, eidx, cursor, fdeg, invdeg,
                                                      Wt1, b1, Wc, P, N);

    // layer 2 (factorized): 6-dim aggregation -> ps/pd
    k_agg3<<<NB, 256, 0, stream>>>(P, eidx, bucketBase, invdeg,
                                   (float4*)ps4, (float4*)pd4, N);

    // edge scoring
    k_edge<<<(E + 255) / 256, 256, 0, stream>>>((const float4*)ps4, (const float4*)pd4,
                                                src, dst, bconst, out, E);
}

// Round 12
// 162.504 us; speedup vs baseline: 4.2232x; 4.2232x over previous
//
#include <hip/hip_runtime.h>
#include <hip/hip_bf16.h>

// ---------------------------------------------------------------------------
// GraphSAGE 2-layer (mean agg) + edge MLP predictor.
// Round 12: revert LDS-atomic experiment (r11, 4.2x regression: 1.9M LDS bank
// conflicts from serialized ds_add_f32). Back to round-9's register-space
// gather (eidx LDS cache + 2-edge unroll + full 64KB W stage, no min-wave
// bound), keeping round-10's s2-fused k_s3 and vectorized k_agg3.
// score[e] = ps[src] + pd[dst] + bconst
// ---------------------------------------------------------------------------

typedef __attribute__((ext_vector_type(8))) short bf16x8;
typedef __attribute__((ext_vector_type(4))) float f32x4;

static __device__ __forceinline__ float bf16lo(unsigned u) {
    return __uint_as_float(u << 16);
}
static __device__ __forceinline__ float bf16hi(unsigned u) {
    return __uint_as_float(u & 0xffff0000u);
}
static __device__ __forceinline__ unsigned short f2bf(float f) {
    unsigned u = __float_as_uint(f);
    unsigned r = 0x7fffu + ((u >> 16) & 1u);  // round to nearest even
    return (unsigned short)((u + r) >> 16);
}
static __device__ __forceinline__ unsigned pack_bf162(float a, float b) {
    return (unsigned)f2bf(a) | ((unsigned)f2bf(b) << 16);
}

#define SORT_BLOCKS 128   // S1/S3 chunk blocks

// ---------------- fused misc: cvt | S1 bucket-hist | Wt1 prep | Wc prep -----
__global__ __launch_bounds__(256) void k_misc(
    const float* __restrict__ x, unsigned short* __restrict__ xb,
    const int* __restrict__ dst, int* __restrict__ H,
    const float* __restrict__ W1s, const float* __restrict__ W1n,
    unsigned short* __restrict__ Wt1,
    const float* __restrict__ W2s, const float* __restrict__ W2n,
    const float* __restrict__ Wp, const float* __restrict__ b2,
    const float* __restrict__ bp, float* __restrict__ Wc,
    float* __restrict__ bconst, int N, int E, int CHUNK)
{
    const int nCvt = (N * 32 + 255) / 256;
    const int b = blockIdx.x;
    const int t = threadIdx.x;

    if (b < nCvt) {
        int i = b * 256 + t;
        if (i < N * 32) {
            float4 v = ((const float4*)x)[i];
            uint2 o;
            o.x = pack_bf162(v.x, v.y);
            o.y = pack_bf162(v.z, v.w);
            *(uint2*)(xb + (size_t)i * 4) = o;
        }
    } else if (b < nCvt + SORT_BLOCKS) {
        // S1: LDS histogram of dst>>8 for this block's edge chunk
        __shared__ int hist[256];
        hist[t] = 0;
        __syncthreads();
        int blk = b - nCvt;
        int start = blk * CHUNK;
        int end = min(start + CHUNK, E);
        for (int e = start + t; e < end; e += 256)
            atomicAdd(&hist[((unsigned)dst[e]) >> 8], 1);
        __syncthreads();
        H[blk * 256 + t] = hist[t];
    } else if (b < nCvt + SORT_BLOCKS + 128) {
        int id = (b - nCvt - SORT_BLOCKS) * 256 + t;  // 32768 total
        int k = id >> 7, n = id & 127;
        float v = (k < 128) ? W1s[k * 128 + n] : W1n[(k - 128) * 128 + n];
        Wt1[n * 256 + k] = f2bf(v);
    } else {
        // Wc[c][j]: j 0-2 u=W2s@Wp_top, 3-5 t=W2n@Wp_top,
        //             6-8 v=W2s@Wp_bot, 9-11 w=W2n@Wp_bot; bconst
        for (int id = t; id < 1539; id += 256) {
            if (id < 1536) {
                int c = id / 12, j = id % 12;
                int q = j / 3, jj = j % 3;
                const float* W2 = (q == 0 || q == 2) ? W2s : W2n;
                int wpoff = (q < 2) ? 0 : 128;
                float s = 0.f;
                for (int m = 0; m < 128; ++m)
                    s += W2[c * 128 + m] * Wp[(wpoff + m) * 3 + jj];
                Wc[c * 12 + j] = s;
            } else {
                int jj = id - 1536;
                float s = bp[jj];
                for (int m = 0; m < 128; ++m)
                    s += b2[m] * (Wp[m * 3 + jj] + Wp[(128 + m) * 3 + jj]);
                bconst[jj] = s;
            }
        }
    }
}

// ---------------- S3 (with fused S2): scatter edges into bucket regions -----
__global__ __launch_bounds__(256) void k_s3(const int* __restrict__ src,
                                            const int* __restrict__ dst,
                                            const int* __restrict__ H,
                                            int* __restrict__ packed,
                                            int* __restrict__ bucketBase,
                                            int E, int CHUNK) {
    __shared__ int lt[256];
    __shared__ int cur[256];
    const int t = threadIdx.x, blk = blockIdx.x;
    int tot = 0, pre = 0;
    for (int b = 0; b < SORT_BLOCKS; ++b) {
        int h = H[b * 256 + t];
        pre += (b < blk) ? h : 0;
        tot += h;
    }
    lt[t] = tot;
    __syncthreads();
    for (int off = 1; off < 256; off <<= 1) {
        int u = (t >= off) ? lt[t - off] : 0;
        __syncthreads();
        lt[t] += u;
        __syncthreads();
    }
    int excl = lt[t] - tot;
    cur[t] = excl + pre;
    if (blk == 0) {
        bucketBase[t] = excl;
        if (t == 0) bucketBase[256] = E;
    }
    __syncthreads();
    int start = blk * CHUNK, end = min(start + CHUNK, E);
    for (int e = start + t; e < end; e += 256) {
        int d = dst[e];
        int p = atomicAdd(&cur[((unsigned)d) >> 8], 1);
        packed[p] = (src[e] & 0xFFFF) | ((d & 255) << 16);  // N<=65536
    }
}

// ---------------- S4: per-bucket counting sort + CSR finalize ---------------
__global__ __launch_bounds__(256) void k_s4(const int* __restrict__ packed,
                                            const int* __restrict__ bucketBase,
                                            int* __restrict__ eidx,
                                            int* __restrict__ cursor,
                                            float* __restrict__ fdeg,
                                            float* __restrict__ invdeg, int N) {
    const int t = threadIdx.x, b = blockIdx.x;
    const int rb = bucketBase[b], re = bucketBase[b + 1];
    __shared__ int cnt[256];
    __shared__ int lt[256];
    __shared__ int cur[256];
    cnt[t] = 0;
    __syncthreads();
    for (int i = rb + t; i < re; i += 256)
        atomicAdd(&cnt[(packed[i] >> 16) & 255], 1);
    __syncthreads();
    int v = cnt[t];
    lt[t] = v;
    __syncthreads();
    for (int off = 1; off < 256; off <<= 1) {
        int u = (t >= off) ? lt[t - off] : 0;
        __syncthreads();
        lt[t] += u;
        __syncthreads();
    }
    int excl = lt[t] - v;
    int node = b * 256 + t;
    if (node < N) {
        cursor[node] = rb + excl + v;  // end offset
        fdeg[node] = (float)v;
        invdeg[node] = 1.0f / fmaxf((float)v, 1.0f);
    }
    cur[t] = rb + excl;
    __syncthreads();
    for (int i = rb + t; i < re; i += 256) {
        int p = packed[i];
        int pos = atomicAdd(&cur[(p >> 16) & 255], 1);
        eidx[pos] = p & 0xFFFF;   // plain src
    }
}

// ---------------- fused gather-aggregate + MFMA GEMM + projection -----------
// Phase A: block's contiguous eidx run staged into LDS (reuses sW space);
//          lane (lrow,lk) aggregates dims {ksb*32+lk*8..+7} of nodes r0,r1
//          in fp32 regs (2-edge unrolled gather), packs bf16 A-fragments.
// Phase B: stage Wt swizzled + Wc; MFMA; epilogue projects h -> P.
__global__ __launch_bounds__(256) void k_gemm_fused(
    const unsigned short* __restrict__ xb,
    const int* __restrict__ eidx, const int* __restrict__ cursor,
    const float* __restrict__ fdeg, const float* __restrict__ invdeg,
    const unsigned short* __restrict__ Wt, const float* __restrict__ bias,
    const float* __restrict__ Wc, float* __restrict__ P, int N)
{
    __shared__ __align__(16) char sW[65536];  // phase A: eidx cache; B: Wt
    __shared__ float sWc[1536];
    const int t = threadIdx.x;
    const int wave = t >> 6, lane = t & 63;
    const int nodeBase = blockIdx.x * 128 + wave * 32;
    const int lrow = lane & 15, lk = lane >> 4;
    const int r0 = nodeBase + lrow, r1 = nodeBase + 16 + lrow;

    // ---- phase A: stage eidx run ----
    int* eidxL = (int*)sW;                       // 16384 entries
    const int nb0 = blockIdx.x * 128;
    const int lastN = min(nb0 + 127, N - 1);
    const int estart = cursor[nb0] - (int)fdeg[nb0];
    const int eend = cursor[lastN];
    const int ecnt = eend - estart;
    const bool ldsOK = (ecnt <= 16384);
    if (ldsOK) {
        for (int i = t; i < ecnt; i += 256) eidxL[i] = eidx[estart + i];
    }
    __syncthreads();

    union { bf16x8 v; unsigned u[4]; } afrag0[4], afrag1[4];

#define GATHER_NODE(R, EP, OFF, AF)                                          \
    {                                                                        \
        float agg[4][8];                                                     \
        _Pragma("unroll") for (int ksb = 0; ksb < 4; ++ksb)                  \
            _Pragma("unroll") for (int i = 0; i < 8; ++i) agg[ksb][i] = 0.f; \
        if ((R) < N) {                                                       \
            int d = (int)fdeg[R];                                            \
            int o = (OFF);                                                   \
            int j = 0;                                                       \
            for (; j + 2 <= d; j += 2) {                                     \
                int s0 = (EP)[o + j], s1 = (EP)[o + j + 1];                  \
                const unsigned short* row0 = xb + (size_t)s0 * 128 + lk * 8; \
                const unsigned short* row1 = xb + (size_t)s1 * 128 + lk * 8; \
                uint4 v0[4], v1[4];                                          \
                _Pragma("unroll") for (int ksb = 0; ksb < 4; ++ksb) {        \
                    v0[ksb] = *(const uint4*)(row0 + ksb * 32);              \
                    v1[ksb] = *(const uint4*)(row1 + ksb * 32);              \
                }                                                            \
                _Pragma("unroll") for (int ksb = 0; ksb < 4; ++ksb) {        \
                    agg[ksb][0] += bf16lo(v0[ksb].x);                        \
                    agg[ksb][1] += bf16hi(v0[ksb].x);                        \
                    agg[ksb][2] += bf16lo(v0[ksb].y);                        \
                    agg[ksb][3] += bf16hi(v0[ksb].y);                        \
                    agg[ksb][4] += bf16lo(v0[ksb].z);                        \
                    agg[ksb][5] += bf16hi(v0[ksb].z);                        \
                    agg[ksb][6] += bf16lo(v0[ksb].w);                        \
                    agg[ksb][7] += bf16hi(v0[ksb].w);                        \
                    agg[ksb][0] += bf16lo(v1[ksb].x);                        \
                    agg[ksb][1] += bf16hi(v1[ksb].x);                        \
                    agg[ksb][2] += bf16lo(v1[ksb].y);                        \
                    agg[ksb][3] += bf16hi(v1[ksb].y);                        \
                    agg[ksb][4] += bf16lo(v1[ksb].z);                        \
                    agg[ksb][5] += bf16hi(v1[ksb].z);                        \
                    agg[ksb][6] += bf16lo(v1[ksb].w);                        \
                    agg[ksb][7] += bf16hi(v1[ksb].w);                        \
                }                                                            \
            }                                                                \
            if (j < d) {                                                     \
                int s0 = (EP)[o + j];                                        \
                const unsigned short* row0 = xb + (size_t)s0 * 128 + lk * 8; \
                _Pragma("unroll") for (int ksb = 0; ksb < 4; ++ksb) {        \
                    uint4 v0 = *(const uint4*)(row0 + ksb * 32);             \
                    agg[ksb][0] += bf16lo(v0.x);                             \
                    agg[ksb][1] += bf16hi(v0.x);                             \
                    agg[ksb][2] += bf16lo(v0.y);                             \
                    agg[ksb][3] += bf16hi(v0.y);                             \
                    agg[ksb][4] += bf16lo(v0.z);                             \
                    agg[ksb][5] += bf16hi(v0.z);                             \
                    agg[ksb][6] += bf16lo(v0.w);                             \
                    agg[ksb][7] += bf16hi(v0.w);                             \
                }                                                            \
            }                                                                \
            float sc = invdeg[R];                                            \
            _Pragma("unroll") for (int ksb = 0; ksb < 4; ++ksb)              \
                _Pragma("unroll") for (int i = 0; i < 4; ++i)                \
                    AF[ksb].u[i] = pack_bf162(agg[ksb][2 * i] * sc,          \
                                              agg[ksb][2 * i + 1] * sc);     \
        } else {                                                             \
            _Pragma("unroll") for (int ksb = 0; ksb < 4; ++ksb)              \
                _Pragma("unroll") for (int i = 0; i < 4; ++i)                \
                    AF[ksb].u[i] = 0u;                                       \
        }                                                                    \
    }

    if (ldsOK) {
        GATHER_NODE(r0, eidxL, (r0 < N ? cursor[r0] - (int)fdeg[r0] - estart : 0), afrag0)
        GATHER_NODE(r1, eidxL, (r1 < N ? cursor[r1] - (int)fdeg[r1] - estart : 0), afrag1)
    } else {
        GATHER_NODE(r0, eidx, (r0 < N ? cursor[r0] - (int)fdeg[r0] : 0), afrag0)
        GATHER_NODE(r1, eidx, (r1 < N ? cursor[r1] - (int)fdeg[r1] : 0), afrag1)
    }
#undef GATHER_NODE

    // ---- phase B: stage weights over the eidx cache ----
    __syncthreads();
#pragma unroll
    for (int i = 0; i < 16; ++i) {
        int o = (i * 256 + t) * 16;
        int n = o >> 9;
        int c = o & 511;
        int sw = (n << 9) | (c ^ ((n & 7) << 4));
        *(float4*)&sW[sw] = *(const float4*)((const char*)Wt + o);
    }
    for (int i = t; i < 1536; i += 256) sWc[i] = Wc[i];

    f32x4 acc[2][8];
#pragma unroll
    for (int rs = 0; rs < 2; ++rs)
#pragma unroll
        for (int nb = 0; nb < 8; ++nb) acc[rs][nb] = (f32x4){0.f, 0.f, 0.f, 0.f};

    __syncthreads();

    for (int ks = 0; ks < 8; ++ks) {
        bf16x8 a0, a1;
        if (ks < 4) {
            const int kk = ks * 32 + lk * 8;
            a0 = (bf16x8){};
            a1 = (bf16x8){};
            if (r0 < N) a0 = *(const bf16x8*)(xb + (size_t)r0 * 128 + kk);
            if (r1 < N) a1 = *(const bf16x8*)(xb + (size_t)r1 * 128 + kk);
        } else {
            a0 = afrag0[ks - 4].v;
            a1 = afrag1[ks - 4].v;
        }
        const int cbase = ks * 64 + lk * 16;  // byte col within 512B row
#pragma unroll
        for (int nb = 0; nb < 8; ++nb) {
            int n = nb * 16 + lrow;
            int sw = (n << 9) | (cbase ^ ((n & 7) << 4));
            bf16x8 b = *(const bf16x8*)&sW[sw];
            acc[0][nb] = __builtin_amdgcn_mfma_f32_16x16x32_bf16(a0, b, acc[0][nb], 0, 0, 0);
            acc[1][nb] = __builtin_amdgcn_mfma_f32_16x16x32_bf16(a1, b, acc[1][nb], 0, 0, 0);
        }
    }

    // Epilogue: C/D layout col = lane&15, row = (lane>>4)*4 + reg [m89].
    // P row layout: self u0..2,v0 at [0..3], v1,v2 at [4..5];
    //               neigh t0..2,w0 at [8..11], w1,w2 at [12..13].
#pragma unroll
    for (int rs = 0; rs < 2; ++rs) {
        float hval[8][4];
#pragma unroll
        for (int nb = 0; nb < 8; ++nb) {
            float bv = bias[nb * 16 + lrow];
#pragma unroll
            for (int r = 0; r < 4; ++r)
                hval[nb][r] = fmaxf(acc[rs][nb][r] + bv, 0.f);
        }
#pragma unroll
        for (int r = 0; r < 4; ++r) {
            float pj[12];
#pragma unroll
            for (int j = 0; j < 12; ++j) pj[j] = 0.f;
#pragma unroll
            for (int nb = 0; nb < 8; ++nb) {
                float hv = hval[nb][r];
                const float* wrow = &sWc[(nb * 16 + lrow) * 12];
#pragma unroll
                for (int j = 0; j < 12; ++j) pj[j] += hv * wrow[j];
            }
#pragma unroll
            for (int off = 8; off; off >>= 1) {
#pragma unroll
                for (int j = 0; j < 12; ++j) pj[j] += __shfl_xor(pj[j], off, 64);
            }
            int node = nodeBase + rs * 16 + lk * 4 + r;
            if (lrow == 0 && node < N) {
                float* prow = &P[(size_t)node * 16];
                *(float4*)(prow + 0)  = make_float4(pj[0], pj[1], pj[2], pj[6]);
                *(float4*)(prow + 4)  = make_float4(pj[7], pj[8], 0.f, 0.f);
                *(float4*)(prow + 8)  = make_float4(pj[3], pj[4], pj[5], pj[9]);
                *(float4*)(prow + 12) = make_float4(pj[10], pj[11], 0.f, 0.f);
            }
        }
    }
}

// ---------------- 6-dim aggregation + finalize ps/pd -----------------------
// One thread per node; 2x float4 loads per edge, 2-edge unrolled.
__global__ __launch_bounds__(256) void k_agg3(const float* __restrict__ P,
                                              const int* __restrict__ eidx,
                                              const int* __restrict__ cursor,
                                              const float* __restrict__ fdeg,
                                              const float* __restrict__ invdeg,
                                              float4* __restrict__ ps4,
                                              float4* __restrict__ pd4, int N) {
    int g = blockIdx.x * 256 + threadIdx.x;
    if (g >= N) return;
    int d = (int)fdeg[g];
    int o = cursor[g] - d;
    float a0 = 0.f, a1 = 0.f, a2 = 0.f, a3 = 0.f, a4 = 0.f, a5 = 0.f;
    int i = 0;
    for (; i + 2 <= d; i += 2) {
        int s0 = eidx[o + i], s1 = eidx[o + i + 1];
        float4 u0 = *(const float4*)&P[(size_t)s0 * 16 + 8];
        float4 u1 = *(const float4*)&P[(size_t)s0 * 16 + 12];
        float4 w0 = *(const float4*)&P[(size_t)s1 * 16 + 8];
        float4 w1 = *(const float4*)&P[(size_t)s1 * 16 + 12];
        a0 += u0.x; a1 += u0.y; a2 += u0.z; a3 += u0.w; a4 += u1.x; a5 += u1.y;
        a0 += w0.x; a1 += w0.y; a2 += w0.z; a3 += w0.w; a4 += w1.x; a5 += w1.y;
    }
    if (i < d) {
        int s0 = eidx[o + i];
        float4 u0 = *(const float4*)&P[(size_t)s0 * 16 + 8];
        float4 u1 = *(const float4*)&P[(size_t)s0 * 16 + 12];
        a0 += u0.x; a1 += u0.y; a2 += u0.z; a3 += u0.w; a4 += u1.x; a5 += u1.y;
    }
    float sc = invdeg[g];
    float4 s0v = *(const float4*)&P[(size_t)g * 16];      // u0,u1,u2,v0
    float4 s1v = *(const float4*)&P[(size_t)g * 16 + 4];  // v1,v2,-,-
    ps4[g] = make_float4(s0v.x + a0 * sc, s0v.y + a1 * sc, s0v.z + a2 * sc, 0.f);
    pd4[g] = make_float4(s0v.w + a3 * sc, s1v.x + a4 * sc, s1v.y + a5 * sc, 0.f);
}

__global__ void k_edge(const float4* __restrict__ ps4, const float4* __restrict__ pd4,
                       const int* __restrict__ src, const int* __restrict__ dst,
                       const float* __restrict__ bconst, float* __restrict__ out, int E)
{
    int e = blockIdx.x * blockDim.x + threadIdx.x;
    if (e >= E) return;
    float4 a = ps4[src[e]];
    float4 b = pd4[dst[e]];
    out[(size_t)e * 3 + 0] = a.x + b.x + bconst[0];
    out[(size_t)e * 3 + 1] = a.y + b.y + bconst[1];
    out[(size_t)e * 3 + 2] = a.z + b.z + bconst[2];
}

extern "C" void kernel_launch(void* const* d_in, const int* in_sizes, int n_in,
                              void* d_out, int out_size, void* d_ws, size_t ws_size,
                              hipStream_t stream)
{
    const float* x   = (const float*)d_in[0];
    // d_in[1] = e (edge features) — unused by the reference score
    const int*   src = (const int*)d_in[2];
    const int*   dst = (const int*)d_in[3];
    const float* W1s = (const float*)d_in[4];
    const float* W1n = (const float*)d_in[5];
    const float* b1  = (const float*)d_in[6];
    const float* W2s = (const float*)d_in[7];
    const float* W2n = (const float*)d_in[8];
    const float* b2  = (const float*)d_in[9];
    const float* Wp  = (const float*)d_in[10];
    const float* bp  = (const float*)d_in[11];
    const int N = in_sizes[0] / 128;
    const int E = in_sizes[2];
    float* out = (float*)d_out;

    const int NB = (N + 255) / 256;            // dst buckets (<=256 for N<=65536)
    const int CHUNK = (E + SORT_BLOCKS - 1) / SORT_BLOCKS;

    // ---- workspace carve (256B aligned chunks) ----
    char* wsp = (char*)d_ws;
    auto alloc = [&](size_t bytes) { char* p = wsp; wsp += (bytes + 255) & ~(size_t)255; return p; };
    float* fdeg     = (float*)alloc((size_t)N * 4);
    float* invdeg   = (float*)alloc((size_t)N * 4);
    int*   cursor   = (int*)alloc((size_t)N * 4);
    int*   eidx     = (int*)alloc((size_t)E * 4);
    int*   packed   = (int*)alloc((size_t)E * 4);
    int*   H        = (int*)alloc((size_t)SORT_BLOCKS * 256 * 4);
    int*   bucketBase = (int*)alloc(260 * 4);
    unsigned short* xb  = (unsigned short*)alloc((size_t)N * 128 * 2);
    unsigned short* Wt1 = (unsigned short*)alloc(256 * 128 * 2);
    float* Wc     = (float*)alloc(1536 * 4);
    float* bconst = (float*)alloc(256);
    float* P      = (float*)alloc((size_t)N * 16 * 4);   // padded 64B rows
    float* ps4    = (float*)alloc((size_t)N * 16);
    float* pd4    = (float*)alloc((size_t)N * 16);

    // fused cvt | S1 bucket-hist | weight prep (all independent)
    const int nCvt = (N * 32 + 255) / 256;
    k_misc<<<nCvt + SORT_BLOCKS + 129, 256, 0, stream>>>(
        x, xb, dst, H, W1s, W1n, Wt1, W2s, W2n, Wp, b2, bp, Wc, bconst, N, E, CHUNK);

    // atomic-free CSR build (s2 fused into s3)
    k_s3<<<SORT_BLOCKS, 256, 0, stream>>>(src, dst, H, packed, bucketBase, E, CHUNK);
    k_s4<<<NB, 256, 0, stream>>>(packed, bucketBase, eidx, cursor, fdeg, invdeg, N);

    // layer 1 + projection, fully fused (agg in registers, h never stored)
    k_gemm_fused<<<(N + 127) / 128, 256, 0, stream>>>(xb, eidx, cursor, fdeg, invdeg,
                                                      Wt1, b1, Wc, P, N);

    // layer 2 (factorized): 6-dim aggregation -> ps/pd
    k_agg3<<<(N + 255) / 256, 256, 0, stream>>>(P, eidx, cursor, fdeg, invdeg,
                                                (float4*)ps4, (float4*)pd4, N);

    // edge scoring
    k_edge<<<(E + 255) / 256, 256, 0, stream>>>((const float4*)ps4, (const float4*)pd4,
                                                src, dst, bconst, out, E);
}